// Round 10
// baseline (161.391 us; speedup 1.0000x reference)
//
#include <hip/hip_runtime.h>
#include <hip/hip_bf16.h>
#include <stdint.h>

// Problem constants
#define NS   8
#define NB   2
#define CK   64
#define CV   64
#define HWN  4096
#define SHW  32768
#define RADIUS_ 0.1f
#define MASK_W  6.103515625e-6f   // 0.2 / 8 / 64 / 64

// Tiling
#define TM    32
#define NW    8
#define QS_STR 68           // fp32 Q stage stride
#define P_STR  40           // bf16 P row stride (fallback kernel only)
#define SBIAS 24.0f
#define LOG2E 1.4426950408889634f
#define SBIAS2 34.624680981135326f   // SBIAS * LOG2E
#define KS    4             // key splits

// Workspace layout
#define KT_ELEMS (NS * NB * CK * HWN)       // 4,194,304
#define KT_BYTES ((size_t)KT_ELEMS * 2)     // 8 MB fp16 transposed K
#define VB_BYTES ((size_t)KT_ELEMS * 2)     // 8 MB bf16 V (interleaved layout)
#define MASKP_OFF (KT_BYTES + VB_BYTES)     // NS*NB*CV f32 partials (4 KB)
#define WS_NEED  (MASKP_OFF + 4096)
#define ONUM_OFF (MASKP_OFF + 4096)
#define ONUM_BYTES ((size_t)KS * NB * HWN * CV * 4)          // 8.4 MB
#define ODEN_OFF (ONUM_OFF + ONUM_BYTES)
#define ODEN_BYTES ((size_t)KS * NB * HWN * 4)
#define WS2      (ODEN_OFF + ODEN_BYTES)                     // ~25.4 MB

typedef __bf16    bf16x8 __attribute__((ext_vector_type(8)));
typedef _Float16  f16x8  __attribute__((ext_vector_type(8)));
typedef float     f32x4  __attribute__((ext_vector_type(4)));
typedef unsigned short u16x8 __attribute__((ext_vector_type(8)));
typedef uint32_t  u32x2 __attribute__((ext_vector_type(2)));
typedef uint32_t  u32x4 __attribute__((ext_vector_type(4)));

__device__ __forceinline__ unsigned short f2bfu(float x) {
  __hip_bfloat16 h = __float2bfloat16(x);
  return __builtin_bit_cast(unsigned short, h);
}
__device__ __forceinline__ bf16x8 ld_bf8_lds(const unsigned short* p) {
  u16x8 u = *(const u16x8*)p;
  return __builtin_bit_cast(bf16x8, u);
}
// async global->LDS, 16B per lane; LDS dest = wave-uniform base + lane*16
__device__ __forceinline__ void load_lds16(const void* g, void* l) {
  __builtin_amdgcn_global_load_lds(
      (const __attribute__((address_space(1))) unsigned int*)g,
      (__attribute__((address_space(3))) unsigned int*)l, 16, 0, 0);
}

// ---------------------------------------------------------------------------
// V layout: within each 32-key group, the 8B half H (keys 4H..4H+3) is stored
// at position p(H) = (H&3)*2 + (H>>2). So 16B chunk q = keys {4q..4q+3,
// 16+4q..16+4q+3}: one b128 LDS read yields a PV B-fragment in pf order.
// prep produces this by PERMUTING THE LOADS (thread t loads halves
// {m, m+4}, m = t&3) and storing one LINEAR 16B chunk -- coalesced both ways.
// ---------------------------------------------------------------------------

// ---------------------------------------------------------------------------
// Fused pre-pass:
//   blocks [0,512):    K fp32 [S,B,CK,HW] -> fp16 transposed kT[b][key][c]
//                      128-hw chunks, XOR-swizzled LDS (conflict-free writes)
//   blocks [512,1536): V fp32 -> bf16 interleaved + mask partial store
// ---------------------------------------------------------------------------
__global__ __launch_bounds__(512) void prep_all(
    const float* __restrict__ keys, const float* __restrict__ vals,
    const float* __restrict__ disp, const int* __restrict__ seq,
    _Float16* __restrict__ kT, unsigned short* __restrict__ vbf,
    float* __restrict__ maskpart)
{
  const int t = threadIdx.x;
  const int blk = blockIdx.x;
  if (blk < 512) {
    // K transpose: LDS [m=128][c=64] fp16, c-chunk XOR-swizzled by (m>>3)&7.
    __shared__ _Float16 lds[128 * 64];      // 16 KB
    const int chunk = blk & 31;             // 32 chunks of 128 hw
    const int s     = (blk >> 5) & 7;
    const int b     = blk >> 8;
    const int hw0   = chunk * 128;
    const int c_st  = t >> 3;               // 0..63
    const int msub  = (t & 7) * 8;          // 0..56
    const int cchunk = c_st >> 3;           // = w (wave id)
    const int clow   = c_st & 7;

    const float* krow = keys + ((size_t)((s * NB + b) * CK + c_st)) * HWN + hw0;
    #pragma unroll
    for (int r = 0; r < 2; ++r) {
      const int m0 = msub + r * 64;
      f32x4 k0 = *(const f32x4*)(krow + m0);
      f32x4 k1 = *(const f32x4*)(krow + m0 + 4);
      // (m>>3)&7 is the same for all 8 m values in [m0, m0+8)
      const int swz = (cchunk ^ ((m0 >> 3) & 7)) * 8 + clow;
      #pragma unroll
      for (int j = 0; j < 4; ++j) {
        lds[(m0 + j)     * 64 + swz] = (_Float16)k0[j];
        lds[(m0 + 4 + j) * 64 + swz] = (_Float16)k1[j];
      }
    }
    __syncthreads();

    _Float16* kout = kT + ((size_t)(b * SHW + s * HWN + hw0)) * CK;
    const int mm = t >> 3;                  // 0..63
    const int cg = t & 7;                   // c-chunk 0..7
    #pragma unroll
    for (int r2 = 0; r2 < 2; ++r2) {
      const int m   = mm + r2 * 64;
      const int swz = cg ^ ((m >> 3) & 7);
      u16x8 v = *(const u16x8*)&lds[m * 64 + swz * 8];
      *(u16x8*)(kout + (size_t)m * CK + cg * 8) = v;
    }
  } else {
    // V path: one (s,b,c) row of 4096 elems per block.
    // Thread t handles halves {m, m+4} (m = t&3) of its 32-elem group ->
    // permuted coalesced loads, one LINEAR 16B store in interleaved order.
    const int r = blk - 512;           // 0..1023
    const int s = r >> 7;
    const int b = (r >> 6) & 1;
    const int c = r & 63;
    float j0 = (float)seq[(b * NS + s) * 2 + 0];
    float j1 = (float)seq[(b * NS + s) * 2 + 1];
    const float dist = sqrtf((j1 - 5.f) * (j1 - 5.f) + (j0 - 5.f) * (j0 - 5.f));

    const int gb = (t >> 2) * 32;      // group base hw
    const int m  = t & 3;
    const int hA = gb + m * 4;         // half m   (4 elems)
    const int hB = hA + 16;            // half m+4 (4 elems)
    f32x4 a  = *(const f32x4*)(vals + (size_t)r * HWN + hA);
    f32x4 bb = *(const f32x4*)(vals + (size_t)r * HWN + hB);
    f32x4 d0 = *(const f32x4*)(disp + (size_t)b * HWN + hA);
    f32x4 d1 = *(const f32x4*)(disp + (size_t)b * HWN + hB);
    u16x8 o;
    float acc = 0.f;
    #pragma unroll
    for (int j = 0; j < 4; ++j) {
      o[j]     = f2bfu(a[j]);
      o[4 + j] = f2bfu(bb[j]);
      if (fabsf(dist * d0[j]) > RADIUS_) acc += a[j];
      if (fabsf(dist * d1[j]) > RADIUS_) acc += bb[j];
    }
    // Linear 16B store: chunk m of the group = halves {m, m+4} (pf order).
    *(u16x8*)(vbf + (size_t)r * HWN + t * 8) = o;

    #pragma unroll
    for (int m2 = 32; m2 >= 1; m2 >>= 1) acc += __shfl_xor(acc, m2);
    __shared__ float red[8];
    if ((t & 63) == 0) red[t >> 6] = acc;
    __syncthreads();
    if (t == 0) {
      float s8 = 0.f;
      #pragma unroll
      for (int j = 0; j < 8; ++j) s8 += red[j];
      maskpart[(b * CV + c) * NS + s] = MASK_W * s8;   // plain store, no atomic
    }
  }
}

// ---------------------------------------------------------------------------
// attn_v6: TM=64, KS=4, XCD-L2 partition. K and V staged via double-buffered
// global_load_lds DMA (round-2 schedule). S^T MFMA with C-init = -SBIAS*log2e
// and Q pre-scaled by log2e, so P = exp2(sf) directly. P->PV uses the
// permuted key labeling; with the interleaved vbf layout the V B-fragment is
// ONE b128 LDS read per cf -- fewer LDS issues, conflict-free.
// Main LDS = 65536 B -> 2 blocks/CU.
// ---------------------------------------------------------------------------
struct __align__(16) Smem6 {
  union {
    struct {
      _Float16       kbuf[2][128 * 64];       // 32768 B [key][c ^ swz(key)]
      unsigned short vbuf[2][64 * 128];       // 32768 B [cv][chunk ^ (cv&7)]
    } main;                                   // 65536 B total
    struct {
      float obuf[4][32][64];                  // 32768 B
      float dbuf[4][32];                      // 512 B
    } epi;
    float qs[64 * QS_STR];                    // 17408 B (prologue only)
  };
};

__global__ __launch_bounds__(512, 4) void attn_v6(
    const _Float16* __restrict__ kT,        // [B][SHW][CK] fp16
    const unsigned short* __restrict__ vbf, // [S,B,CV,HW] bf16 interleaved
    const float* __restrict__ query,        // [B,CK,HW] fp32
    float* __restrict__ onum,               // [KS][B][HWN][CV]
    float* __restrict__ odenom)             // [KS][B][HWN]
{
  __shared__ Smem6 sm;
  const int t    = threadIdx.x;
  const int w    = t >> 6;
  const int lane = t & 63;
  const int quad = lane >> 4;
  const int l15  = lane & 15;
  const int kq   = w & 3;
  const int rg   = w >> 2;
  const int bidx = blockIdx.x;
  const int xcd  = bidx & 7;               // (ks<<1)|b -> one XCD per K/V slice
  const int b    = xcd & 1;
  const int ks   = xcd >> 1;
  const int tile = bidx >> 3;              // 0..63
  const int n0   = tile * 64;

  // --- Stage Q (64 rows) transposed fp32, then fp16 B-fragments (pre-scaled
  //     by log2e so exp(S-24) == exp2(sf) with C-init -SBIAS2) ---
  {
    const int qc   = t >> 3;
    const int noff = (t & 7) * 8;
    const int slot = qc ^ ((t & 7) << 2);
    const float* qp = query + (size_t)(b * CK + qc) * HWN + n0 + noff;
    f32x4 q0 = *(const f32x4*)(qp);
    f32x4 q1 = *(const f32x4*)(qp + 4);
    #pragma unroll
    for (int j = 0; j < 4; ++j) {
      sm.qs[(noff + j)     * QS_STR + slot] = q0[j];
      sm.qs[(noff + 4 + j) * QS_STR + slot] = q1[j];
    }
  }
  __syncthreads();
  f16x8 qf[2][2];
  #pragma unroll
  for (int f = 0; f < 2; ++f) {
    const int n  = rg * 32 + f * 16 + l15;
    const int sw = ((n >> 3) & 7) << 2;
    const float* base = &sm.qs[n * QS_STR];
    #pragma unroll
    for (int h = 0; h < 2; ++h) {
      const int c0 = (h * 32 + quad * 8) ^ sw;
      f32x4 a  = *(const f32x4*)(base + c0);
      f32x4 bb = *(const f32x4*)(base + (c0 ^ 4));
      f16x8 q;
      #pragma unroll
      for (int j = 0; j < 4; ++j) {
        q[j]     = (_Float16)(a[j]  * LOG2E);
        q[4 + j] = (_Float16)(bb[j] * LOG2E);
      }
      qf[f][h] = q;
    }
  }
  __syncthreads();  // qs reads done; kbuf/vbuf region free for DMA

  f32x4 Of[2][4];
  f32x4 Ol[2];
  #pragma unroll
  for (int f = 0; f < 2; ++f) {
    #pragma unroll
    for (int cf = 0; cf < 4; ++cf) Of[f][cf] = (f32x4){0.f, 0.f, 0.f, 0.f};
    Ol[f] = (f32x4){0.f, 0.f, 0.f, 0.f};
  }
  bf16x8 vones;
  #pragma unroll
  for (int i = 0; i < 8; ++i)
    vones[i] = __builtin_bit_cast(__bf16, (unsigned short)0x3F80);

  // --- DMA addressing (2 K-insts + 2 V-insts per wave per tile) ---
  uint32_t ksrc_off[2];
  int      kldsoff[2];
  uint32_t vsrc_off[2];   // ushort units, relative to frame/batch base + hw0
  int      vldsoff[2];
  #pragma unroll
  for (int j = 0; j < 2; ++j) {
    const int inst = w * 2 + j;                 // 0..15
    const int kl   = inst * 8 + (lane >> 3);    // staged key 0..127
    const int cqs  = lane & 7;
    ksrc_off[j] = (uint32_t)(kl * 128 + ((cqs ^ (kl & 7)) * 16));
    kldsoff[j]  = inst * 1024;
    const int cv  = inst * 4 + (lane >> 4);     // staged cv row 0..63
    const int chs = (lane & 15) ^ (cv & 7);     // source chunk (16B = 8 bf16)
    vsrc_off[j] = (uint32_t)(cv * HWN + chs * 8);
    vldsoff[j]  = inst * 1024;
  }
  const char* kgbase = (const char*)(kT + (size_t)b * SHW * CK);
  const int   kbase0 = ks * (SHW / KS);

  // Prologue: DMA tile 0 into buf 0
  {
    const char* kg = kgbase + (size_t)kbase0 * 128;
    load_lds16(kg + ksrc_off[0], (char*)sm.main.kbuf[0] + kldsoff[0]);
    load_lds16(kg + ksrc_off[1], (char*)sm.main.kbuf[0] + kldsoff[1]);
    const int sfrm0 = kbase0 >> 12;
    const unsigned short* vg =
        vbf + (size_t)((sfrm0 * NB + b) * CV) * HWN + (kbase0 & 4095);
    load_lds16(vg + vsrc_off[0], (char*)sm.main.vbuf[0] + vldsoff[0]);
    load_lds16(vg + vsrc_off[1], (char*)sm.main.vbuf[0] + vldsoff[1]);
  }

  for (int it = 0; it < 64; ++it) {
    const int cur  = it & 1;
    const int key0 = kbase0 + it * 128;

    __syncthreads();  // tile `it` landed (drains vmcnt); buf[cur^1] free

    // --- prefetch tile it+1 into the other buffer ---
    if (it < 63) {
      const int keyn = key0 + 128;
      const char* kg = kgbase + (size_t)keyn * 128;
      load_lds16(kg + ksrc_off[0], (char*)sm.main.kbuf[cur ^ 1] + kldsoff[0]);
      load_lds16(kg + ksrc_off[1], (char*)sm.main.kbuf[cur ^ 1] + kldsoff[1]);
      const int sfrmn = keyn >> 12;
      const unsigned short* vg =
          vbf + (size_t)((sfrmn * NB + b) * CV) * HWN + (keyn & 4095);
      load_lds16(vg + vsrc_off[0], (char*)sm.main.vbuf[cur ^ 1] + vldsoff[0]);
      load_lds16(vg + vsrc_off[1], (char*)sm.main.vbuf[cur ^ 1] + vldsoff[1]);
    }

    // --- K A-fragments from LDS (swizzled) ---
    f16x8 kf[2][2];
    #pragma unroll
    for (int g = 0; g < 2; ++g) {
      const int kl  = kq * 32 + g * 16 + l15;
      const int swz = kl & 7;
      const _Float16* kb = &sm.main.kbuf[cur][kl * 64];
      #pragma unroll
      for (int h = 0; h < 2; ++h) {
        const int slot = (h * 4 + quad) ^ swz;
        kf[g][h] = *(const f16x8*)(kb + slot * 8);
      }
    }

    // --- V B-fragments: interleaved layout -> ONE b128 per cf at chunk
    //     (kq*4+quad)^swz, content = keys {g0: quad*4+r, g1: 16+quad*4+r} ---
    bf16x8 vf[4];
    {
      const int ch = kq * 4 + quad;
      #pragma unroll
      for (int cf = 0; cf < 4; ++cf) {
        const int cv  = cf * 16 + l15;
        const int swz = cv & 7;
        vf[cf] = ld_bf8_lds(&sm.main.vbuf[cur][cv * 128 + ((ch ^ swz) << 3)]);
      }
    }

    // --- S^T = K @ Q^T with folded bias: sf = S*log2e - SBIAS2 ---
    f32x4 sf[2][2];
    #pragma unroll
    for (int g = 0; g < 2; ++g)
      #pragma unroll
      for (int f = 0; f < 2; ++f) {
        f32x4 acc = (f32x4){-SBIAS2, -SBIAS2, -SBIAS2, -SBIAS2};
        acc = __builtin_amdgcn_mfma_f32_16x16x32_f16(kf[g][0], qf[f][0], acc, 0, 0, 0);
        acc = __builtin_amdgcn_mfma_f32_16x16x32_f16(kf[g][1], qf[f][1], acc, 0, 0, 0);
        sf[g][f] = acc;
      }

    // --- P = 2^sf, truncation-packed via v_perm; pf is lane-local (pi) ---
    #pragma unroll
    for (int f = 0; f < 2; ++f) {
      uint32_t pk[2][2];
      #pragma unroll
      for (int g = 0; g < 2; ++g) {
        float e0 = __builtin_amdgcn_exp2f(sf[g][f][0]);
        float e1 = __builtin_amdgcn_exp2f(sf[g][f][1]);
        float e2 = __builtin_amdgcn_exp2f(sf[g][f][2]);
        float e3 = __builtin_amdgcn_exp2f(sf[g][f][3]);
        pk[g][0] = __builtin_amdgcn_perm(__builtin_bit_cast(uint32_t, e1),
                                         __builtin_bit_cast(uint32_t, e0),
                                         0x07060302u);
        pk[g][1] = __builtin_amdgcn_perm(__builtin_bit_cast(uint32_t, e3),
                                         __builtin_bit_cast(uint32_t, e2),
                                         0x07060302u);
      }
      bf16x8 pf = __builtin_bit_cast(bf16x8,
          (u32x4){pk[0][0], pk[0][1], pk[1][0], pk[1][1]});

      #pragma unroll
      for (int cf = 0; cf < 4; ++cf)
        Of[f][cf] = __builtin_amdgcn_mfma_f32_16x16x32_bf16(pf, vf[cf], Of[f][cf], 0, 0, 0);
      Ol[f] = __builtin_amdgcn_mfma_f32_16x16x32_bf16(pf, vones, Ol[f], 0, 0, 0);
    }
  }

  __syncthreads();  // all waves done with main region before epi alias

  // --- Epilogue: reduce 4 kq waves per rg phase, store partials ---
  #pragma unroll
  for (int phase = 0; phase < 2; ++phase) {
    if (rg == phase) {
      #pragma unroll
      for (int f = 0; f < 2; ++f)
        #pragma unroll
        for (int r = 0; r < 4; ++r) {
          const int row = f * 16 + quad * 4 + r;
          if (l15 == 0) sm.epi.dbuf[kq][row] = Ol[f][r];
          #pragma unroll
          for (int cf = 0; cf < 4; ++cf)
            sm.epi.obuf[kq][row][cf * 16 + l15] = Of[f][cf][r];
        }
    }
    __syncthreads();
    {
      const int row = t >> 4;
      const int v4  = (t & 15) * 4;
      f32x4 acc = *(const f32x4*)&sm.epi.obuf[0][row][v4];
      #pragma unroll
      for (int q = 1; q < 4; ++q)
        acc += *(const f32x4*)&sm.epi.obuf[q][row][v4];
      *(f32x4*)&onum[((size_t)(ks * NB + b) * HWN + n0 + phase * 32 + row) * CV + v4] = acc;
      if (t < 32) {
        float d = sm.epi.dbuf[0][t] + sm.epi.dbuf[1][t] +
                  sm.epi.dbuf[2][t] + sm.epi.dbuf[3][t];
        odenom[(size_t)(ks * NB + b) * HWN + n0 + phase * 32 + t] = d;
      }
    }
    __syncthreads();
  }
}

// ---------------------------------------------------------------------------
// Finalize: out[b][v][hw] = sum_ks onum / sum_ks odenom + mask
// ---------------------------------------------------------------------------
__global__ __launch_bounds__(256) void finalize_k(
    const float* __restrict__ onum, const float* __restrict__ odenom,
    const float* __restrict__ maskpart, float* __restrict__ out)
{
  __shared__ float tile[64][68];
  __shared__ float dinv[64];
  __shared__ float ml[64];
  const int t   = threadIdx.x;
  const int b   = blockIdx.x >> 6;
  const int hw0 = (blockIdx.x & 63) * 64;

  #pragma unroll
  for (int pass = 0; pass < 4; ++pass) {
    const int row = pass * 16 + (t >> 4);
    const int v4  = (t & 15) * 4;
    f32x4 acc = (f32x4){0.f, 0.f, 0.f, 0.f};
    #pragma unroll
    for (int ks = 0; ks < KS; ++ks)
      acc += *(const f32x4*)&onum[((size_t)(ks * NB + b) * HWN + hw0 + row) * CV + v4];
    *(f32x4*)&tile[row][v4] = acc;
  }
  if (t < 64) {
    float d = 0.f;
    #pragma unroll
    for (int ks = 0; ks < KS; ++ks)
      d += odenom[(size_t)(ks * NB + b) * HWN + hw0 + t];
    dinv[t] = 1.f / fmaxf(d, 1e-30f);
  }
  if (t >= 64 && t < 128) {
    float m = 0.f;
    #pragma unroll
    for (int s = 0; s < NS; ++s) m += maskpart[(b * CV + (t - 64)) * NS + s];
    ml[t - 64] = m;
  }
  __syncthreads();

  #pragma unroll
  for (int pass = 0; pass < 4; ++pass) {
    const int v   = pass * 16 + (t >> 4);
    const int hw4 = (t & 15) * 4;
    f32x4 o;
    #pragma unroll
    for (int j = 0; j < 4; ++j)
      o[j] = tile[hw4 + j][v] * dinv[hw4 + j] + ml[v];
    *(f32x4*)&out[((size_t)(b * CV + v)) * HWN + hw0 + hw4] = o;
  }
}

// ---------------------------------------------------------------------------
// Round-6 attention (fallback, small ws) -- reads interleaved vbf
// ---------------------------------------------------------------------------
struct __align__(16) SmemF {
  union {
    float qs[TM * QS_STR];
    unsigned short p[NW][2][16 * P_STR];
    struct {
      float obuf[NW][TM][CV];
      float lbuf[NW][TM];
    } epi;
  };
};

__global__ __launch_bounds__(512) void attn_fast(
    const _Float16* __restrict__ kT, const unsigned short* __restrict__ vbf,
    const float* __restrict__ query, const float* __restrict__ maskpart,
    float* __restrict__ out)
{
  __shared__ SmemF sm;
  const int t    = threadIdx.x;
  const int w    = t >> 6;
  const int lane = t & 63;
  const int quad = lane >> 4;
  const int l15  = lane & 15;
  const int bidx = blockIdx.x;
  const int b    = bidx & 1;
  const int n0   = ((bidx >> 1) & 127) * TM;

  if (t < 256) {
    const int qc   = t >> 2;
    const int noff = (t & 3) * 8;
    const int slot = qc ^ ((t & 3) << 2);
    const float* qp = query + (size_t)(b * CK + qc) * HWN + n0 + noff;
    f32x4 q0 = *(const f32x4*)(qp);
    f32x4 q1 = *(const f32x4*)(qp + 4);
    #pragma unroll
    for (int j = 0; j < 4; ++j) {
      sm.qs[(noff + j)     * QS_STR + slot] = q0[j];
      sm.qs[(noff + 4 + j) * QS_STR + slot] = q1[j];
    }
  }
  __syncthreads();
  f16x8 qf[2][2];
  #pragma unroll
  for (int f = 0; f < 2; ++f) {
    const int n  = f * 16 + l15;
    const int sw = ((n >> 3) & 7) << 2;
    const float* base = &sm.qs[n * QS_STR];
    #pragma unroll
    for (int h = 0; h < 2; ++h) {
      const int c0 = (h * 32 + quad * 8) ^ sw;
      f32x4 a  = *(const f32x4*)(base + c0);
      f32x4 bb = *(const f32x4*)(base + (c0 ^ 4));
      f16x8 q;
      #pragma unroll
      for (int j = 0; j < 4; ++j) { q[j] = (_Float16)a[j]; q[4 + j] = (_Float16)bb[j]; }
      qf[f][h] = q;
    }
  }
  __syncthreads();

  f32x4 Of[2][4];
  f32x4 Ol[2];
  #pragma unroll
  for (int f = 0; f < 2; ++f) {
    #pragma unroll
    for (int cf = 0; cf < 4; ++cf) Of[f][cf] = (f32x4){0.f, 0.f, 0.f, 0.f};
    Ol[f] = (f32x4){0.f, 0.f, 0.f, 0.f};
  }
  bf16x8 vones;
  #pragma unroll
  for (int i = 0; i < 8; ++i)
    vones[i] = __builtin_bit_cast(__bf16, (unsigned short)0x3F80);

  const _Float16* kbase = kT + (size_t)b * SHW * CK;

  for (int it = 0; it < SHW / 256; ++it) {
    const int key0 = it * 256 + w * 32;
    f16x8 kf[2][2];
    #pragma unroll
    for (int g = 0; g < 2; ++g)
      #pragma unroll
      for (int h = 0; h < 2; ++h)
        kf[g][h] = *(const f16x8*)(kbase +
            (size_t)(key0 + g * 16 + l15) * CK + h * 32 + quad * 8);

    const int s   = it >> 4;
    const int hwg = (it & 15) * 256 + w * 32;
    const int pa  = ((2 * quad) & 3) * 2 + (quad >> 1);
    const int pb  = ((2 * quad + 1) & 3) * 2 + (quad >> 1);
    bf16x8 vf[4];
    #pragma unroll
    for (int cf = 0; cf < 4; ++cf) {
      const unsigned short* rowp = vbf +
          ((size_t)((s * NB + b) * CV + cf * 16 + l15)) * HWN + hwg;
      u32x2 lo = *(const u32x2*)(rowp + pa * 4);
      u32x2 hi = *(const u32x2*)(rowp + pb * 4);
      vf[cf] = __builtin_bit_cast(bf16x8, (u32x4){lo.x, lo.y, hi.x, hi.y});
    }

    f32x4 sfv[2][2];
    #pragma unroll
    for (int f = 0; f < 2; ++f)
      #pragma unroll
      for (int g = 0; g < 2; ++g) {
        f32x4 acc = (f32x4){0.f, 0.f, 0.f, 0.f};
        acc = __builtin_amdgcn_mfma_f32_16x16x32_f16(qf[f][0], kf[g][0], acc, 0, 0, 0);
        acc = __builtin_amdgcn_mfma_f32_16x16x32_f16(qf[f][1], kf[g][1], acc, 0, 0, 0);
        sfv[f][g] = acc;
      }

    #pragma unroll
    for (int f = 0; f < 2; ++f)
      #pragma unroll
      for (int g = 0; g < 2; ++g)
        #pragma unroll
        for (int r = 0; r < 4; ++r)
          sfv[f][g][r] = __expf(sfv[f][g][r] - SBIAS);

    #pragma unroll
    for (int f = 0; f < 2; ++f)
      #pragma unroll
      for (int g = 0; g < 2; ++g)
        #pragma unroll
        for (int r = 0; r < 4; ++r)
          sm.p[w][f][(quad * 4 + r) * P_STR + g * 16 + l15] = f2bfu(sfv[f][g][r]);
    asm volatile("s_waitcnt lgkmcnt(0)" ::: "memory");
    bf16x8 pf[2];
    #pragma unroll
    for (int f = 0; f < 2; ++f)
      pf[f] = ld_bf8_lds(&sm.p[w][f][l15 * P_STR + quad * 8]);

    #pragma unroll
    for (int f = 0; f < 2; ++f) {
      #pragma unroll
      for (int cf = 0; cf < 4; ++cf)
        Of[f][cf] = __builtin_amdgcn_mfma_f32_16x16x32_bf16(pf[f], vf[cf], Of[f][cf], 0, 0, 0);
      Ol[f] = __builtin_amdgcn_mfma_f32_16x16x32_bf16(pf[f], vones, Ol[f], 0, 0, 0);
    }
  }

  __syncthreads();
  #pragma unroll
  for (int f = 0; f < 2; ++f)
    #pragma unroll
    for (int r = 0; r < 4; ++r) {
      const int row = f * 16 + quad * 4 + r;
      if (l15 == 0) sm.epi.lbuf[w][row] = Ol[f][r];
      #pragma unroll
      for (int cf = 0; cf < 4; ++cf)
        sm.epi.obuf[w][row][cf * 16 + l15] = Of[f][cf][r];
    }
  __syncthreads();
  {
    const int n   = t & 31;
    const int vhi = t >> 5;
    float denom = 0.f;
    #pragma unroll
    for (int ww = 0; ww < NW; ++ww) denom += sm.epi.lbuf[ww][n];
    const float inv = 1.f / fmaxf(denom, 1e-30f);
    #pragma unroll
    for (int g = 0; g < 4; ++g) {
      const int v = vhi + 16 * g;
      float num = 0.f;
      #pragma unroll
      for (int ww = 0; ww < NW; ++ww) num += sm.epi.obuf[ww][n][v];
      float mlv = 0.f;
      #pragma unroll
      for (int s = 0; s < NS; ++s) mlv += maskpart[(b * CV + v) * NS + s];
      out[((size_t)(b * CV + v)) * HWN + n0 + n] = num * inv + mlv;
    }
  }
}

// ---------------------------------------------------------------------------
extern "C" void kernel_launch(void* const* d_in, const int* in_sizes, int n_in,
                              void* d_out, int out_size, void* d_ws, size_t ws_size,
                              hipStream_t stream) {
  const float* keys  = (const float*)d_in[0];
  const float* vals  = (const float*)d_in[1];
  const float* query = (const float*)d_in[2];
  const float* disp  = (const float*)d_in[3];
  const int*   seq   = (const int*)d_in[4];
  float*       out   = (float*)d_out;

  _Float16*       kT    = (_Float16*)d_ws;
  unsigned short* vbf   = (unsigned short*)((char*)d_ws + KT_BYTES);
  float*          maskp = (float*)((char*)d_ws + MASKP_OFF);

  prep_all<<<512 + NB * NS * CV, 512, 0, stream>>>(keys, vals, disp, seq,
                                                   kT, vbf, maskp);

  if (ws_size >= WS2) {
    float* onum   = (float*)((char*)d_ws + ONUM_OFF);
    float* odenom = (float*)((char*)d_ws + ODEN_OFF);
    attn_v6<<<NB * 64 * KS, 512, 0, stream>>>(kT, vbf, query, onum, odenom);
    finalize_k<<<NB * (HWN / 64), 256, 0, stream>>>(onum, odenom, maskp, out);
  } else {
    attn_fast<<<NB * (HWN / TM), 512, 0, stream>>>(kT, vbf, query, maskp, out);
  }
}

// Round 11
// 159.774 us; speedup vs baseline: 1.0101x; 1.0101x over previous
//
#include <hip/hip_runtime.h>
#include <hip/hip_bf16.h>
#include <stdint.h>

// Problem constants
#define NS   8
#define NB   2
#define CK   64
#define CV   64
#define HWN  4096
#define SHW  32768
#define RADIUS_ 0.1f
#define MASK_W  6.103515625e-6f   // 0.2 / 8 / 64 / 64

// Tiling
#define TM    32
#define NW    8
#define QS_STR 68           // fp32 Q stage stride
#define P_STR  40           // bf16 P row stride (fallback kernel only)
#define SBIAS 24.0f
#define LOG2E 1.4426950408889634f
#define SBIAS2 34.624680981135326f   // SBIAS * LOG2E
#define KS    4             // key splits

// Workspace layout
#define KT_ELEMS (NS * NB * CK * HWN)       // 4,194,304
#define KT_BYTES ((size_t)KT_ELEMS * 2)     // 8 MB fp16 transposed K
#define VB_BYTES ((size_t)KT_ELEMS * 2)     // 8 MB bf16 V (interleaved layout)
#define MASKP_OFF (KT_BYTES + VB_BYTES)     // NS*NB*CV f32 partials (4 KB)
#define WS_NEED  (MASKP_OFF + 4096)
#define ONUM_OFF (MASKP_OFF + 4096)
#define ONUM_BYTES ((size_t)KS * NB * HWN * CV * 4)          // 8.4 MB
#define ODEN_OFF (ONUM_OFF + ONUM_BYTES)
#define ODEN_BYTES ((size_t)KS * NB * HWN * 4)
#define WS2      (ODEN_OFF + ODEN_BYTES)                     // ~25.4 MB

typedef __bf16    bf16x8 __attribute__((ext_vector_type(8)));
typedef _Float16  f16x8  __attribute__((ext_vector_type(8)));
typedef float     f32x4  __attribute__((ext_vector_type(4)));
typedef unsigned short u16x8 __attribute__((ext_vector_type(8)));
typedef uint32_t  u32x2 __attribute__((ext_vector_type(2)));
typedef uint32_t  u32x4 __attribute__((ext_vector_type(4)));

__device__ __forceinline__ unsigned short f2bfu(float x) {
  __hip_bfloat16 h = __float2bfloat16(x);
  return __builtin_bit_cast(unsigned short, h);
}
__device__ __forceinline__ bf16x8 ld_bf8_lds(const unsigned short* p) {
  u16x8 u = *(const u16x8*)p;
  return __builtin_bit_cast(bf16x8, u);
}
// async global->LDS, 16B per lane; LDS dest = wave-uniform base + lane*16
__device__ __forceinline__ void load_lds16(const void* g, void* l) {
  __builtin_amdgcn_global_load_lds(
      (const __attribute__((address_space(1))) unsigned int*)g,
      (__attribute__((address_space(3))) unsigned int*)l, 16, 0, 0);
}

// ---------------------------------------------------------------------------
// V layout: within each 32-key group, the 8B half H (keys 4H..4H+3) is stored
// at position p(H) = (H&3)*2 + (H>>2). So 16B chunk q = keys {4q..4q+3,
// 16+4q..16+4q+3}: one b128 LDS read yields a PV B-fragment in pf order.
// prep produces this by PERMUTING THE LOADS (thread t loads halves
// {m, m+4}, m = t&3) and storing one LINEAR 16B chunk -- coalesced both ways.
// ---------------------------------------------------------------------------

// ---------------------------------------------------------------------------
// Fused pre-pass:
//   blocks [0,512):    K fp32 [S,B,CK,HW] -> fp16 transposed kT[b][key][c]
//                      128-hw chunks, XOR-swizzled LDS (conflict-free writes)
//   blocks [512,1536): V fp32 -> bf16 interleaved + mask partial store
// ---------------------------------------------------------------------------
__global__ __launch_bounds__(512) void prep_all(
    const float* __restrict__ keys, const float* __restrict__ vals,
    const float* __restrict__ disp, const int* __restrict__ seq,
    _Float16* __restrict__ kT, unsigned short* __restrict__ vbf,
    float* __restrict__ maskpart)
{
  const int t = threadIdx.x;
  const int blk = blockIdx.x;
  if (blk < 512) {
    // K transpose: LDS [m=128][c=64] fp16, c-chunk XOR-swizzled by (m>>3)&7.
    __shared__ _Float16 lds[128 * 64];      // 16 KB
    const int chunk = blk & 31;             // 32 chunks of 128 hw
    const int s     = (blk >> 5) & 7;
    const int b     = blk >> 8;
    const int hw0   = chunk * 128;
    const int c_st  = t >> 3;               // 0..63
    const int msub  = (t & 7) * 8;          // 0..56
    const int cchunk = c_st >> 3;           // = w (wave id)
    const int clow   = c_st & 7;

    const float* krow = keys + ((size_t)((s * NB + b) * CK + c_st)) * HWN + hw0;
    #pragma unroll
    for (int r = 0; r < 2; ++r) {
      const int m0 = msub + r * 64;
      f32x4 k0 = *(const f32x4*)(krow + m0);
      f32x4 k1 = *(const f32x4*)(krow + m0 + 4);
      // (m>>3)&7 is the same for all 8 m values in [m0, m0+8)
      const int swz = (cchunk ^ ((m0 >> 3) & 7)) * 8 + clow;
      #pragma unroll
      for (int j = 0; j < 4; ++j) {
        lds[(m0 + j)     * 64 + swz] = (_Float16)k0[j];
        lds[(m0 + 4 + j) * 64 + swz] = (_Float16)k1[j];
      }
    }
    __syncthreads();

    _Float16* kout = kT + ((size_t)(b * SHW + s * HWN + hw0)) * CK;
    const int mm = t >> 3;                  // 0..63
    const int cg = t & 7;                   // c-chunk 0..7
    #pragma unroll
    for (int r2 = 0; r2 < 2; ++r2) {
      const int m   = mm + r2 * 64;
      const int swz = cg ^ ((m >> 3) & 7);
      u16x8 v = *(const u16x8*)&lds[m * 64 + swz * 8];
      *(u16x8*)(kout + (size_t)m * CK + cg * 8) = v;
    }
  } else {
    // V path: one (s,b,c) row of 4096 elems per block.
    // Thread t handles halves {m, m+4} (m = t&3) of its 32-elem group ->
    // permuted coalesced loads, one LINEAR 16B store in interleaved order.
    const int r = blk - 512;           // 0..1023
    const int s = r >> 7;
    const int b = (r >> 6) & 1;
    const int c = r & 63;
    float j0 = (float)seq[(b * NS + s) * 2 + 0];
    float j1 = (float)seq[(b * NS + s) * 2 + 1];
    const float dist = sqrtf((j1 - 5.f) * (j1 - 5.f) + (j0 - 5.f) * (j0 - 5.f));

    const int gb = (t >> 2) * 32;      // group base hw
    const int m  = t & 3;
    const int hA = gb + m * 4;         // half m   (4 elems)
    const int hB = hA + 16;            // half m+4 (4 elems)
    f32x4 a  = *(const f32x4*)(vals + (size_t)r * HWN + hA);
    f32x4 bb = *(const f32x4*)(vals + (size_t)r * HWN + hB);
    f32x4 d0 = *(const f32x4*)(disp + (size_t)b * HWN + hA);
    f32x4 d1 = *(const f32x4*)(disp + (size_t)b * HWN + hB);
    u16x8 o;
    float acc = 0.f;
    #pragma unroll
    for (int j = 0; j < 4; ++j) {
      o[j]     = f2bfu(a[j]);
      o[4 + j] = f2bfu(bb[j]);
      if (fabsf(dist * d0[j]) > RADIUS_) acc += a[j];
      if (fabsf(dist * d1[j]) > RADIUS_) acc += bb[j];
    }
    // Linear 16B store: chunk m of the group = halves {m, m+4} (pf order).
    *(u16x8*)(vbf + (size_t)r * HWN + t * 8) = o;

    #pragma unroll
    for (int m2 = 32; m2 >= 1; m2 >>= 1) acc += __shfl_xor(acc, m2);
    __shared__ float red[8];
    if ((t & 63) == 0) red[t >> 6] = acc;
    __syncthreads();
    if (t == 0) {
      float s8 = 0.f;
      #pragma unroll
      for (int j = 0; j < 8; ++j) s8 += red[j];
      maskpart[(b * CV + c) * NS + s] = MASK_W * s8;   // plain store, no atomic
    }
  }
}

// ---------------------------------------------------------------------------
// attn_v6: TM=64, KS=4, XCD-L2 partition. K and V staged via double-buffered
// global_load_lds DMA (round-2 schedule). S^T MFMA with C-init = -SBIAS*log2e
// and Q pre-scaled by log2e, so P = exp2(sf) directly. P->PV uses the
// permuted key labeling; with the interleaved vbf layout the V B-fragment is
// ONE b128 LDS read per cf -- fewer LDS issues, conflict-free.
// Main LDS = 65536 B -> 2 blocks/CU.
// ---------------------------------------------------------------------------
struct __align__(16) Smem6 {
  union {
    struct {
      _Float16       kbuf[2][128 * 64];       // 32768 B [key][c ^ swz(key)]
      unsigned short vbuf[2][64 * 128];       // 32768 B [cv][chunk ^ (cv&7)]
    } main;                                   // 65536 B total
    struct {
      float obuf[4][32][64];                  // 32768 B
      float dbuf[4][32];                      // 512 B
    } epi;
    float qs[64 * QS_STR];                    // 17408 B (prologue only)
  };
};

__global__ __launch_bounds__(512, 4) void attn_v6(
    const _Float16* __restrict__ kT,        // [B][SHW][CK] fp16
    const unsigned short* __restrict__ vbf, // [S,B,CV,HW] bf16 interleaved
    const float* __restrict__ query,        // [B,CK,HW] fp32
    float* __restrict__ onum,               // [KS][B][HWN][CV]
    float* __restrict__ odenom)             // [KS][B][HWN]
{
  __shared__ Smem6 sm;
  const int t    = threadIdx.x;
  const int w    = t >> 6;
  const int lane = t & 63;
  const int quad = lane >> 4;
  const int l15  = lane & 15;
  const int kq   = w & 3;
  const int rg   = w >> 2;
  const int bidx = blockIdx.x;
  const int xcd  = bidx & 7;               // (ks<<1)|b -> one XCD per K/V slice
  const int b    = xcd & 1;
  const int ks   = xcd >> 1;
  const int tile = bidx >> 3;              // 0..63
  const int n0   = tile * 64;

  // --- Stage Q (64 rows) transposed fp32, then fp16 B-fragments (pre-scaled
  //     by log2e so exp(S-24) == exp2(sf) with C-init -SBIAS2) ---
  {
    const int qc   = t >> 3;
    const int noff = (t & 7) * 8;
    const int slot = qc ^ ((t & 7) << 2);
    const float* qp = query + (size_t)(b * CK + qc) * HWN + n0 + noff;
    f32x4 q0 = *(const f32x4*)(qp);
    f32x4 q1 = *(const f32x4*)(qp + 4);
    #pragma unroll
    for (int j = 0; j < 4; ++j) {
      sm.qs[(noff + j)     * QS_STR + slot] = q0[j];
      sm.qs[(noff + 4 + j) * QS_STR + slot] = q1[j];
    }
  }
  __syncthreads();
  f16x8 qf[2][2];
  #pragma unroll
  for (int f = 0; f < 2; ++f) {
    const int n  = rg * 32 + f * 16 + l15;
    const int sw = ((n >> 3) & 7) << 2;
    const float* base = &sm.qs[n * QS_STR];
    #pragma unroll
    for (int h = 0; h < 2; ++h) {
      const int c0 = (h * 32 + quad * 8) ^ sw;
      f32x4 a  = *(const f32x4*)(base + c0);
      f32x4 bb = *(const f32x4*)(base + (c0 ^ 4));
      f16x8 q;
      #pragma unroll
      for (int j = 0; j < 4; ++j) {
        q[j]     = (_Float16)(a[j]  * LOG2E);
        q[4 + j] = (_Float16)(bb[j] * LOG2E);
      }
      qf[f][h] = q;
    }
  }
  __syncthreads();  // qs reads done; kbuf/vbuf region free for DMA

  f32x4 Of[2][4];
  f32x4 Ol[2];
  #pragma unroll
  for (int f = 0; f < 2; ++f) {
    #pragma unroll
    for (int cf = 0; cf < 4; ++cf) Of[f][cf] = (f32x4){0.f, 0.f, 0.f, 0.f};
    Ol[f] = (f32x4){0.f, 0.f, 0.f, 0.f};
  }
  bf16x8 vones;
  #pragma unroll
  for (int i = 0; i < 8; ++i)
    vones[i] = __builtin_bit_cast(__bf16, (unsigned short)0x3F80);

  // --- DMA addressing (2 K-insts + 2 V-insts per wave per tile) ---
  uint32_t ksrc_off[2];
  int      kldsoff[2];
  uint32_t vsrc_off[2];   // ushort units, relative to frame/batch base + hw0
  int      vldsoff[2];
  #pragma unroll
  for (int j = 0; j < 2; ++j) {
    const int inst = w * 2 + j;                 // 0..15
    const int kl   = inst * 8 + (lane >> 3);    // staged key 0..127
    const int cqs  = lane & 7;
    ksrc_off[j] = (uint32_t)(kl * 128 + ((cqs ^ (kl & 7)) * 16));
    kldsoff[j]  = inst * 1024;
    const int cv  = inst * 4 + (lane >> 4);     // staged cv row 0..63
    const int chs = (lane & 15) ^ (cv & 7);     // source chunk (16B = 8 bf16)
    vsrc_off[j] = (uint32_t)(cv * HWN + chs * 8);
    vldsoff[j]  = inst * 1024;
  }
  const char* kgbase = (const char*)(kT + (size_t)b * SHW * CK);
  const int   kbase0 = ks * (SHW / KS);

  // Prologue: DMA tile 0 into buf 0
  {
    const char* kg = kgbase + (size_t)kbase0 * 128;
    load_lds16(kg + ksrc_off[0], (char*)sm.main.kbuf[0] + kldsoff[0]);
    load_lds16(kg + ksrc_off[1], (char*)sm.main.kbuf[0] + kldsoff[1]);
    const int sfrm0 = kbase0 >> 12;
    const unsigned short* vg =
        vbf + (size_t)((sfrm0 * NB + b) * CV) * HWN + (kbase0 & 4095);
    load_lds16(vg + vsrc_off[0], (char*)sm.main.vbuf[0] + vldsoff[0]);
    load_lds16(vg + vsrc_off[1], (char*)sm.main.vbuf[0] + vldsoff[1]);
  }

  for (int it = 0; it < 64; ++it) {
    const int cur  = it & 1;
    const int key0 = kbase0 + it * 128;

    __syncthreads();  // tile `it` landed (drains vmcnt); buf[cur^1] free

    // --- prefetch tile it+1 into the other buffer ---
    if (it < 63) {
      const int keyn = key0 + 128;
      const char* kg = kgbase + (size_t)keyn * 128;
      load_lds16(kg + ksrc_off[0], (char*)sm.main.kbuf[cur ^ 1] + kldsoff[0]);
      load_lds16(kg + ksrc_off[1], (char*)sm.main.kbuf[cur ^ 1] + kldsoff[1]);
      const int sfrmn = keyn >> 12;
      const unsigned short* vg =
          vbf + (size_t)((sfrmn * NB + b) * CV) * HWN + (keyn & 4095);
      load_lds16(vg + vsrc_off[0], (char*)sm.main.vbuf[cur ^ 1] + vldsoff[0]);
      load_lds16(vg + vsrc_off[1], (char*)sm.main.vbuf[cur ^ 1] + vldsoff[1]);
    }

    // --- K A-fragments from LDS (swizzled) ---
    f16x8 kf[2][2];
    #pragma unroll
    for (int g = 0; g < 2; ++g) {
      const int kl  = kq * 32 + g * 16 + l15;
      const int swz = kl & 7;
      const _Float16* kb = &sm.main.kbuf[cur][kl * 64];
      #pragma unroll
      for (int h = 0; h < 2; ++h) {
        const int slot = (h * 4 + quad) ^ swz;
        kf[g][h] = *(const f16x8*)(kb + slot * 8);
      }
    }

    // --- V B-fragments: interleaved layout -> ONE b128 per cf at chunk
    //     (kq*4+quad)^swz, content = keys {g0: quad*4+r, g1: 16+quad*4+r} ---
    bf16x8 vf[4];
    {
      const int ch = kq * 4 + quad;
      #pragma unroll
      for (int cf = 0; cf < 4; ++cf) {
        const int cv  = cf * 16 + l15;
        const int swz = cv & 7;
        vf[cf] = ld_bf8_lds(&sm.main.vbuf[cur][cv * 128 + ((ch ^ swz) << 3)]);
      }
    }

    // --- S^T = K @ Q^T with folded bias: sf = S*log2e - SBIAS2 ---
    f32x4 sf[2][2];
    #pragma unroll
    for (int g = 0; g < 2; ++g)
      #pragma unroll
      for (int f = 0; f < 2; ++f) {
        f32x4 acc = (f32x4){-SBIAS2, -SBIAS2, -SBIAS2, -SBIAS2};
        acc = __builtin_amdgcn_mfma_f32_16x16x32_f16(kf[g][0], qf[f][0], acc, 0, 0, 0);
        acc = __builtin_amdgcn_mfma_f32_16x16x32_f16(kf[g][1], qf[f][1], acc, 0, 0, 0);
        sf[g][f] = acc;
      }

    // --- P = 2^sf, truncation-packed via v_perm; pf is lane-local (pi) ---
    #pragma unroll
    for (int f = 0; f < 2; ++f) {
      uint32_t pk[2][2];
      #pragma unroll
      for (int g = 0; g < 2; ++g) {
        float e0 = __builtin_amdgcn_exp2f(sf[g][f][0]);
        float e1 = __builtin_amdgcn_exp2f(sf[g][f][1]);
        float e2 = __builtin_amdgcn_exp2f(sf[g][f][2]);
        float e3 = __builtin_amdgcn_exp2f(sf[g][f][3]);
        pk[g][0] = __builtin_amdgcn_perm(__builtin_bit_cast(uint32_t, e1),
                                         __builtin_bit_cast(uint32_t, e0),
                                         0x07060302u);
        pk[g][1] = __builtin_amdgcn_perm(__builtin_bit_cast(uint32_t, e3),
                                         __builtin_bit_cast(uint32_t, e2),
                                         0x07060302u);
      }
      bf16x8 pf = __builtin_bit_cast(bf16x8,
          (u32x4){pk[0][0], pk[0][1], pk[1][0], pk[1][1]});

      #pragma unroll
      for (int cf = 0; cf < 4; ++cf)
        Of[f][cf] = __builtin_amdgcn_mfma_f32_16x16x32_bf16(pf, vf[cf], Of[f][cf], 0, 0, 0);
      Ol[f] = __builtin_amdgcn_mfma_f32_16x16x32_bf16(pf, vones, Ol[f], 0, 0, 0);
    }
  }

  __syncthreads();  // all waves done with main region before epi alias

  // --- Epilogue: reduce 4 kq waves per rg phase, store partials ---
  #pragma unroll
  for (int phase = 0; phase < 2; ++phase) {
    if (rg == phase) {
      #pragma unroll
      for (int f = 0; f < 2; ++f)
        #pragma unroll
        for (int r = 0; r < 4; ++r) {
          const int row = f * 16 + quad * 4 + r;
          if (l15 == 0) sm.epi.dbuf[kq][row] = Ol[f][r];
          #pragma unroll
          for (int cf = 0; cf < 4; ++cf)
            sm.epi.obuf[kq][row][cf * 16 + l15] = Of[f][cf][r];
        }
    }
    __syncthreads();
    {
      const int row = t >> 4;
      const int v4  = (t & 15) * 4;
      f32x4 acc = *(const f32x4*)&sm.epi.obuf[0][row][v4];
      #pragma unroll
      for (int q = 1; q < 4; ++q)
        acc += *(const f32x4*)&sm.epi.obuf[q][row][v4];
      *(f32x4*)&onum[((size_t)(ks * NB + b) * HWN + n0 + phase * 32 + row) * CV + v4] = acc;
      if (t < 32) {
        float d = sm.epi.dbuf[0][t] + sm.epi.dbuf[1][t] +
                  sm.epi.dbuf[2][t] + sm.epi.dbuf[3][t];
        odenom[(size_t)(ks * NB + b) * HWN + n0 + phase * 32 + t] = d;
      }
    }
    __syncthreads();
  }
}

// ---------------------------------------------------------------------------
// Finalize: out[b][v][hw] = sum_ks onum / sum_ks odenom + mask
// Grid NB*(HWN/16) = 512 blocks (16 hw rows each) -> 2 blocks/CU, all CUs
// busy; 4x the latency-hiding of the old 128-block version (cross-XCD onum
// reads are remote-L2/HBM, ~900 cyc -- parallelism is the only lever).
// ---------------------------------------------------------------------------
__global__ __launch_bounds__(256) void finalize_k(
    const float* __restrict__ onum, const float* __restrict__ odenom,
    const float* __restrict__ maskpart, float* __restrict__ out)
{
  __shared__ float tile[16][68];
  __shared__ float dinv[16];
  __shared__ float ml[64];
  const int t   = threadIdx.x;
  const int b   = blockIdx.x >> 8;          // 256 blocks per batch
  const int hw0 = (blockIdx.x & 255) * 16;

  {
    const int row = t >> 4;                 // 0..15
    const int v4  = (t & 15) * 4;
    f32x4 acc = (f32x4){0.f, 0.f, 0.f, 0.f};
    #pragma unroll
    for (int ks = 0; ks < KS; ++ks)
      acc += *(const f32x4*)&onum[((size_t)(ks * NB + b) * HWN + hw0 + row) * CV + v4];
    *(f32x4*)&tile[row][v4] = acc;
  }
  if (t < 16) {
    float d = 0.f;
    #pragma unroll
    for (int ks = 0; ks < KS; ++ks)
      d += odenom[(size_t)(ks * NB + b) * HWN + hw0 + t];
    dinv[t] = 1.f / fmaxf(d, 1e-30f);
  }
  if (t >= 64 && t < 128) {
    float m = 0.f;
    #pragma unroll
    for (int s = 0; s < NS; ++s) m += maskpart[(b * CV + (t - 64)) * NS + s];
    ml[t - 64] = m;
  }
  __syncthreads();

  {
    const int v   = t >> 2;                 // 0..63
    const int hw4 = (t & 3) * 4;            // 0..12
    f32x4 o;
    #pragma unroll
    for (int j = 0; j < 4; ++j)
      o[j] = tile[hw4 + j][v] * dinv[hw4 + j] + ml[v];
    *(f32x4*)&out[((size_t)(b * CV + v)) * HWN + hw0 + hw4] = o;
  }
}

// ---------------------------------------------------------------------------
// Round-6 attention (fallback, small ws) -- reads interleaved vbf
// ---------------------------------------------------------------------------
struct __align__(16) SmemF {
  union {
    float qs[TM * QS_STR];
    unsigned short p[NW][2][16 * P_STR];
    struct {
      float obuf[NW][TM][CV];
      float lbuf[NW][TM];
    } epi;
  };
};

__global__ __launch_bounds__(512) void attn_fast(
    const _Float16* __restrict__ kT, const unsigned short* __restrict__ vbf,
    const float* __restrict__ query, const float* __restrict__ maskpart,
    float* __restrict__ out)
{
  __shared__ SmemF sm;
  const int t    = threadIdx.x;
  const int w    = t >> 6;
  const int lane = t & 63;
  const int quad = lane >> 4;
  const int l15  = lane & 15;
  const int bidx = blockIdx.x;
  const int b    = bidx & 1;
  const int n0   = ((bidx >> 1) & 127) * TM;

  if (t < 256) {
    const int qc   = t >> 2;
    const int noff = (t & 3) * 8;
    const int slot = qc ^ ((t & 3) << 2);
    const float* qp = query + (size_t)(b * CK + qc) * HWN + n0 + noff;
    f32x4 q0 = *(const f32x4*)(qp);
    f32x4 q1 = *(const f32x4*)(qp + 4);
    #pragma unroll
    for (int j = 0; j < 4; ++j) {
      sm.qs[(noff + j)     * QS_STR + slot] = q0[j];
      sm.qs[(noff + 4 + j) * QS_STR + slot] = q1[j];
    }
  }
  __syncthreads();
  f16x8 qf[2][2];
  #pragma unroll
  for (int f = 0; f < 2; ++f) {
    const int n  = f * 16 + l15;
    const int sw = ((n >> 3) & 7) << 2;
    const float* base = &sm.qs[n * QS_STR];
    #pragma unroll
    for (int h = 0; h < 2; ++h) {
      const int c0 = (h * 32 + quad * 8) ^ sw;
      f32x4 a  = *(const f32x4*)(base + c0);
      f32x4 bb = *(const f32x4*)(base + (c0 ^ 4));
      f16x8 q;
      #pragma unroll
      for (int j = 0; j < 4; ++j) { q[j] = (_Float16)a[j]; q[4 + j] = (_Float16)bb[j]; }
      qf[f][h] = q;
    }
  }
  __syncthreads();

  f32x4 Of[2][4];
  f32x4 Ol[2];
  #pragma unroll
  for (int f = 0; f < 2; ++f) {
    #pragma unroll
    for (int cf = 0; cf < 4; ++cf) Of[f][cf] = (f32x4){0.f, 0.f, 0.f, 0.f};
    Ol[f] = (f32x4){0.f, 0.f, 0.f, 0.f};
  }
  bf16x8 vones;
  #pragma unroll
  for (int i = 0; i < 8; ++i)
    vones[i] = __builtin_bit_cast(__bf16, (unsigned short)0x3F80);

  const _Float16* kbase = kT + (size_t)b * SHW * CK;

  for (int it = 0; it < SHW / 256; ++it) {
    const int key0 = it * 256 + w * 32;
    f16x8 kf[2][2];
    #pragma unroll
    for (int g = 0; g < 2; ++g)
      #pragma unroll
      for (int h = 0; h < 2; ++h)
        kf[g][h] = *(const f16x8*)(kbase +
            (size_t)(key0 + g * 16 + l15) * CK + h * 32 + quad * 8);

    const int s   = it >> 4;
    const int hwg = (it & 15) * 256 + w * 32;
    const int pa  = ((2 * quad) & 3) * 2 + (quad >> 1);
    const int pb  = ((2 * quad + 1) & 3) * 2 + (quad >> 1);
    bf16x8 vf[4];
    #pragma unroll
    for (int cf = 0; cf < 4; ++cf) {
      const unsigned short* rowp = vbf +
          ((size_t)((s * NB + b) * CV + cf * 16 + l15)) * HWN + hwg;
      u32x2 lo = *(const u32x2*)(rowp + pa * 4);
      u32x2 hi = *(const u32x2*)(rowp + pb * 4);
      vf[cf] = __builtin_bit_cast(bf16x8, (u32x4){lo.x, lo.y, hi.x, hi.y});
    }

    f32x4 sfv[2][2];
    #pragma unroll
    for (int f = 0; f < 2; ++f)
      #pragma unroll
      for (int g = 0; g < 2; ++g) {
        f32x4 acc = (f32x4){0.f, 0.f, 0.f, 0.f};
        acc = __builtin_amdgcn_mfma_f32_16x16x32_f16(qf[f][0], kf[g][0], acc, 0, 0, 0);
        acc = __builtin_amdgcn_mfma_f32_16x16x32_f16(qf[f][1], kf[g][1], acc, 0, 0, 0);
        sfv[f][g] = acc;
      }

    #pragma unroll
    for (int f = 0; f < 2; ++f)
      #pragma unroll
      for (int g = 0; g < 2; ++g)
        #pragma unroll
        for (int r = 0; r < 4; ++r)
          sfv[f][g][r] = __expf(sfv[f][g][r] - SBIAS);

    #pragma unroll
    for (int f = 0; f < 2; ++f)
      #pragma unroll
      for (int g = 0; g < 2; ++g)
        #pragma unroll
        for (int r = 0; r < 4; ++r)
          sm.p[w][f][(quad * 4 + r) * P_STR + g * 16 + l15] = f2bfu(sfv[f][g][r]);
    asm volatile("s_waitcnt lgkmcnt(0)" ::: "memory");
    bf16x8 pf[2];
    #pragma unroll
    for (int f = 0; f < 2; ++f)
      pf[f] = ld_bf8_lds(&sm.p[w][f][l15 * P_STR + quad * 8]);

    #pragma unroll
    for (int f = 0; f < 2; ++f) {
      #pragma unroll
      for (int cf = 0; cf < 4; ++cf)
        Of[f][cf] = __builtin_amdgcn_mfma_f32_16x16x32_bf16(pf[f], vf[cf], Of[f][cf], 0, 0, 0);
      Ol[f] = __builtin_amdgcn_mfma_f32_16x16x32_bf16(pf[f], vones, Ol[f], 0, 0, 0);
    }
  }

  __syncthreads();
  #pragma unroll
  for (int f = 0; f < 2; ++f)
    #pragma unroll
    for (int r = 0; r < 4; ++r) {
      const int row = f * 16 + quad * 4 + r;
      if (l15 == 0) sm.epi.lbuf[w][row] = Ol[f][r];
      #pragma unroll
      for (int cf = 0; cf < 4; ++cf)
        sm.epi.obuf[w][row][cf * 16 + l15] = Of[f][cf][r];
    }
  __syncthreads();
  {
    const int n   = t & 31;
    const int vhi = t >> 5;
    float denom = 0.f;
    #pragma unroll
    for (int ww = 0; ww < NW; ++ww) denom += sm.epi.lbuf[ww][n];
    const float inv = 1.f / fmaxf(denom, 1e-30f);
    #pragma unroll
    for (int g = 0; g < 4; ++g) {
      const int v = vhi + 16 * g;
      float num = 0.f;
      #pragma unroll
      for (int ww = 0; ww < NW; ++ww) num += sm.epi.obuf[ww][n][v];
      float mlv = 0.f;
      #pragma unroll
      for (int s = 0; s < NS; ++s) mlv += maskpart[(b * CV + v) * NS + s];
      out[((size_t)(b * CV + v)) * HWN + n0 + n] = num * inv + mlv;
    }
  }
}

// ---------------------------------------------------------------------------
extern "C" void kernel_launch(void* const* d_in, const int* in_sizes, int n_in,
                              void* d_out, int out_size, void* d_ws, size_t ws_size,
                              hipStream_t stream) {
  const float* keys  = (const float*)d_in[0];
  const float* vals  = (const float*)d_in[1];
  const float* query = (const float*)d_in[2];
  const float* disp  = (const float*)d_in[3];
  const int*   seq   = (const int*)d_in[4];
  float*       out   = (float*)d_out;

  _Float16*       kT    = (_Float16*)d_ws;
  unsigned short* vbf   = (unsigned short*)((char*)d_ws + KT_BYTES);
  float*          maskp = (float*)((char*)d_ws + MASKP_OFF);

  prep_all<<<512 + NB * NS * CV, 512, 0, stream>>>(keys, vals, disp, seq,
                                                   kT, vbf, maskp);

  if (ws_size >= WS2) {
    float* onum   = (float*)((char*)d_ws + ONUM_OFF);
    float* odenom = (float*)((char*)d_ws + ODEN_OFF);
    attn_v6<<<NB * 64 * KS, 512, 0, stream>>>(kT, vbf, query, onum, odenom);
    finalize_k<<<NB * (HWN / 16), 256, 0, stream>>>(onum, odenom, maskp, out);
  } else {
    attn_fast<<<NB * (HWN / TM), 512, 0, stream>>>(kT, vbf, query, maskp, out);
  }
}

// Round 12
// 155.236 us; speedup vs baseline: 1.0397x; 1.0292x over previous
//
#include <hip/hip_runtime.h>
#include <hip/hip_bf16.h>
#include <stdint.h>

// Problem constants
#define NS   8
#define NB   2
#define CK   64
#define CV   64
#define HWN  4096
#define SHW  32768
#define RADIUS_ 0.1f
#define MASK_W  6.103515625e-6f   // 0.2 / 8 / 64 / 64

// Tiling
#define TM    32
#define NW    8
#define QS_STR 68           // fp32 Q stage stride
#define P_STR  40           // bf16 P row stride (fallback kernel only)
#define SBIAS 24.0f
#define LOG2E 1.4426950408889634f
#define SBIAS2 34.624680981135326f   // SBIAS * LOG2E
#define KS    4             // key splits

// Workspace layout
#define KT_ELEMS (NS * NB * CK * HWN)       // 4,194,304
#define KT_BYTES ((size_t)KT_ELEMS * 2)     // 8 MB fp16 transposed K
#define VB_BYTES ((size_t)KT_ELEMS * 2)     // 8 MB bf16 V (interleaved layout)
#define MASKP_OFF (KT_BYTES + VB_BYTES)     // NS*NB*CV f32 partials (4 KB)
#define WS_NEED  (MASKP_OFF + 4096)
#define ONUM_OFF (MASKP_OFF + 4096)
#define ONUM_BYTES ((size_t)KS * NB * HWN * CV * 4)          // 8.4 MB
#define ODEN_OFF (ONUM_OFF + ONUM_BYTES)
#define ODEN_BYTES ((size_t)KS * NB * HWN * 4)
#define WS2      (ODEN_OFF + ODEN_BYTES)                     // ~25.4 MB

typedef __bf16    bf16x8 __attribute__((ext_vector_type(8)));
typedef _Float16  f16x8  __attribute__((ext_vector_type(8)));
typedef float     f32x4  __attribute__((ext_vector_type(4)));
typedef unsigned short u16x8 __attribute__((ext_vector_type(8)));
typedef uint32_t  u32x2 __attribute__((ext_vector_type(2)));
typedef uint32_t  u32x4 __attribute__((ext_vector_type(4)));

__device__ __forceinline__ unsigned short f2bfu(float x) {
  __hip_bfloat16 h = __float2bfloat16(x);
  return __builtin_bit_cast(unsigned short, h);
}
__device__ __forceinline__ bf16x8 ld_bf8_lds(const unsigned short* p) {
  u16x8 u = *(const u16x8*)p;
  return __builtin_bit_cast(bf16x8, u);
}
// async global->LDS, 16B per lane; LDS dest = wave-uniform base + lane*16
__device__ __forceinline__ void load_lds16(const void* g, void* l) {
  __builtin_amdgcn_global_load_lds(
      (const __attribute__((address_space(1))) unsigned int*)g,
      (__attribute__((address_space(3))) unsigned int*)l, 16, 0, 0);
}

// ---------------------------------------------------------------------------
// V layout: within each 32-key group, the 8B half H (keys 4H..4H+3) is stored
// at position p(H) = (H&3)*2 + (H>>2). So 16B chunk q = keys {4q..4q+3,
// 16+4q..16+4q+3}: one b128 LDS read yields a PV B-fragment in pf order.
// prep produces this by PERMUTING THE LOADS (thread t loads halves
// {m, m+4}, m = t&3) and storing one LINEAR 16B chunk -- coalesced both ways.
// ---------------------------------------------------------------------------

// ---------------------------------------------------------------------------
// Fused pre-pass:
//   blocks [0,512):    K fp32 [S,B,CK,HW] -> fp16 transposed kT[b][key][c]
//                      128-hw chunks, XOR-swizzled LDS (conflict-free writes)
//   blocks [512,1536): V fp32 -> bf16 interleaved + mask partial store
// ---------------------------------------------------------------------------
__global__ __launch_bounds__(512) void prep_all(
    const float* __restrict__ keys, const float* __restrict__ vals,
    const float* __restrict__ disp, const int* __restrict__ seq,
    _Float16* __restrict__ kT, unsigned short* __restrict__ vbf,
    float* __restrict__ maskpart)
{
  const int t = threadIdx.x;
  const int blk = blockIdx.x;
  if (blk < 512) {
    // K transpose: LDS [m=128][c=64] fp16, c-chunk XOR-swizzled by (m>>3)&7.
    __shared__ _Float16 lds[128 * 64];      // 16 KB
    const int chunk = blk & 31;             // 32 chunks of 128 hw
    const int s     = (blk >> 5) & 7;
    const int b     = blk >> 8;
    const int hw0   = chunk * 128;
    const int c_st  = t >> 3;               // 0..63
    const int msub  = (t & 7) * 8;          // 0..56
    const int cchunk = c_st >> 3;           // = w (wave id)
    const int clow   = c_st & 7;

    const float* krow = keys + ((size_t)((s * NB + b) * CK + c_st)) * HWN + hw0;
    #pragma unroll
    for (int r = 0; r < 2; ++r) {
      const int m0 = msub + r * 64;
      f32x4 k0 = *(const f32x4*)(krow + m0);
      f32x4 k1 = *(const f32x4*)(krow + m0 + 4);
      // (m>>3)&7 is the same for all 8 m values in [m0, m0+8)
      const int swz = (cchunk ^ ((m0 >> 3) & 7)) * 8 + clow;
      #pragma unroll
      for (int j = 0; j < 4; ++j) {
        lds[(m0 + j)     * 64 + swz] = (_Float16)k0[j];
        lds[(m0 + 4 + j) * 64 + swz] = (_Float16)k1[j];
      }
    }
    __syncthreads();

    _Float16* kout = kT + ((size_t)(b * SHW + s * HWN + hw0)) * CK;
    const int mm = t >> 3;                  // 0..63
    const int cg = t & 7;                   // c-chunk 0..7
    #pragma unroll
    for (int r2 = 0; r2 < 2; ++r2) {
      const int m   = mm + r2 * 64;
      const int swz = cg ^ ((m >> 3) & 7);
      u16x8 v = *(const u16x8*)&lds[m * 64 + swz * 8];
      *(u16x8*)(kout + (size_t)m * CK + cg * 8) = v;
    }
  } else {
    // V path: one (s,b,c) row of 4096 elems per block.
    // Thread t handles halves {m, m+4} (m = t&3) of its 32-elem group ->
    // permuted coalesced loads, one LINEAR 16B store in interleaved order.
    const int r = blk - 512;           // 0..1023
    const int s = r >> 7;
    const int b = (r >> 6) & 1;
    const int c = r & 63;
    float j0 = (float)seq[(b * NS + s) * 2 + 0];
    float j1 = (float)seq[(b * NS + s) * 2 + 1];
    const float dist = sqrtf((j1 - 5.f) * (j1 - 5.f) + (j0 - 5.f) * (j0 - 5.f));

    const int gb = (t >> 2) * 32;      // group base hw
    const int m  = t & 3;
    const int hA = gb + m * 4;         // half m   (4 elems)
    const int hB = hA + 16;            // half m+4 (4 elems)
    f32x4 a  = *(const f32x4*)(vals + (size_t)r * HWN + hA);
    f32x4 bb = *(const f32x4*)(vals + (size_t)r * HWN + hB);
    f32x4 d0 = *(const f32x4*)(disp + (size_t)b * HWN + hA);
    f32x4 d1 = *(const f32x4*)(disp + (size_t)b * HWN + hB);
    u16x8 o;
    float acc = 0.f;
    #pragma unroll
    for (int j = 0; j < 4; ++j) {
      o[j]     = f2bfu(a[j]);
      o[4 + j] = f2bfu(bb[j]);
      if (fabsf(dist * d0[j]) > RADIUS_) acc += a[j];
      if (fabsf(dist * d1[j]) > RADIUS_) acc += bb[j];
    }
    // Linear 16B store: chunk m of the group = halves {m, m+4} (pf order).
    *(u16x8*)(vbf + (size_t)r * HWN + t * 8) = o;

    #pragma unroll
    for (int m2 = 32; m2 >= 1; m2 >>= 1) acc += __shfl_xor(acc, m2);
    __shared__ float red[8];
    if ((t & 63) == 0) red[t >> 6] = acc;
    __syncthreads();
    if (t == 0) {
      float s8 = 0.f;
      #pragma unroll
      for (int j = 0; j < 8; ++j) s8 += red[j];
      maskpart[(b * CV + c) * NS + s] = MASK_W * s8;   // plain store, no atomic
    }
  }
}

// ---------------------------------------------------------------------------
// attn_v7 (r8 best): 1024-thread blocks (16 waves = 4 rg x 4 kq), 128 Q-rows
// per block sharing ONE 128-key K/V tile per iteration (per-CU staging
// halved). KS=4 XCD-L2 partition (grid 256 = 1 block/CU). S^T MFMA with
// C-init = -SBIAS*log2e and Q pre-scaled by log2e -> P = exp2(sf) directly;
// lane-local P via permuted key labeling; interleaved vbf -> one b128 V read
// per cf. s_setprio(1) around MFMA clusters. Main LDS = 65536 B.
// ---------------------------------------------------------------------------
struct __align__(16) Smem6 {
  union {
    struct {
      _Float16       kbuf[2][128 * 64];       // 32768 B [key][c ^ swz(key)]
      unsigned short vbuf[2][64 * 128];       // 32768 B [cv][chunk ^ (cv&7)]
    } main;                                   // 65536 B total
    struct {
      float obuf[4][32][64];                  // 32768 B
      float dbuf[4][32];                      // 512 B
    } epi;
    float qs[128 * QS_STR];                   // 34816 B (prologue only)
  };
};

__global__ __launch_bounds__(1024, 4) void attn_v6(
    const _Float16* __restrict__ kT,        // [B][SHW][CK] fp16
    const unsigned short* __restrict__ vbf, // [S,B,CV,HW] bf16 interleaved
    const float* __restrict__ query,        // [B,CK,HW] fp32
    float* __restrict__ onum,               // [KS][B][HWN][CV]
    float* __restrict__ odenom)             // [KS][B][HWN]
{
  __shared__ Smem6 sm;
  const int t    = threadIdx.x;
  const int w    = t >> 6;                 // 0..15
  const int lane = t & 63;
  const int quad = lane >> 4;
  const int l15  = lane & 15;
  const int kq   = w & 3;
  const int rg   = w >> 2;                 // 0..3
  const int bidx = blockIdx.x;
  const int xcd  = bidx & 7;               // (ks<<1)|b -> one XCD per K/V slice
  const int b    = xcd & 1;
  const int ks   = xcd >> 1;
  const int tile = bidx >> 3;              // 0..31
  const int n0   = tile * 128;

  // --- Stage Q (128 rows) transposed fp32, then fp16 B-fragments (pre-scaled
  //     by log2e so exp(S-24) == exp2(sf) with C-init -SBIAS2) ---
  {
    const int qc   = t >> 4;               // channel 0..63
    const int noff = (t & 15) * 8;         // rows 0..120
    const int slot = qc ^ ((t & 15) << 2);
    const float* qp = query + (size_t)(b * CK + qc) * HWN + n0 + noff;
    f32x4 q0 = *(const f32x4*)(qp);
    f32x4 q1 = *(const f32x4*)(qp + 4);
    #pragma unroll
    for (int j = 0; j < 4; ++j) {
      sm.qs[(noff + j)     * QS_STR + slot] = q0[j];
      sm.qs[(noff + 4 + j) * QS_STR + slot] = q1[j];
    }
  }
  __syncthreads();
  f16x8 qf[2][2];
  #pragma unroll
  for (int f = 0; f < 2; ++f) {
    const int n  = rg * 32 + f * 16 + l15;   // 0..127
    const int sw = ((n >> 3) & 15) << 2;
    const float* base = &sm.qs[n * QS_STR];
    #pragma unroll
    for (int h = 0; h < 2; ++h) {
      const int c0 = (h * 32 + quad * 8) ^ sw;
      f32x4 a  = *(const f32x4*)(base + c0);
      f32x4 bb = *(const f32x4*)(base + (c0 ^ 4));
      f16x8 q;
      #pragma unroll
      for (int j = 0; j < 4; ++j) {
        q[j]     = (_Float16)(a[j]  * LOG2E);
        q[4 + j] = (_Float16)(bb[j] * LOG2E);
      }
      qf[f][h] = q;
    }
  }
  __syncthreads();  // qs reads done; kbuf/vbuf region free for DMA

  f32x4 Of[2][4];
  f32x4 Ol[2];
  #pragma unroll
  for (int f = 0; f < 2; ++f) {
    #pragma unroll
    for (int cf = 0; cf < 4; ++cf) Of[f][cf] = (f32x4){0.f, 0.f, 0.f, 0.f};
    Ol[f] = (f32x4){0.f, 0.f, 0.f, 0.f};
  }
  bf16x8 vones;
  #pragma unroll
  for (int i = 0; i < 8; ++i)
    vones[i] = __builtin_bit_cast(__bf16, (unsigned short)0x3F80);

  // --- DMA addressing (1 K-inst + 1 V-inst per wave per tile; 16 waves) ---
  const int kl   = w * 8 + (lane >> 3);       // staged key 0..127
  const uint32_t ksrc_off = (uint32_t)(kl * 128 + (((lane & 7) ^ (kl & 7)) * 16));
  const int kldsoff = w * 1024;
  const int cvr  = w * 4 + (lane >> 4);       // staged cv row 0..63
  const uint32_t vsrc_off =
      (uint32_t)(cvr * HWN + (((lane & 15) ^ (cvr & 7)) * 8));
  const int vldsoff = w * 1024;

  const char* kgbase = (const char*)(kT + (size_t)b * SHW * CK);
  const int   kbase0 = ks * (SHW / KS);

  // Prologue: DMA tile 0 into buf 0
  {
    const char* kg = kgbase + (size_t)kbase0 * 128;
    load_lds16(kg + ksrc_off, (char*)sm.main.kbuf[0] + kldsoff);
    const int sfrm0 = kbase0 >> 12;
    const unsigned short* vg =
        vbf + (size_t)((sfrm0 * NB + b) * CV) * HWN + (kbase0 & 4095);
    load_lds16(vg + vsrc_off, (char*)sm.main.vbuf[0] + vldsoff);
  }

  for (int it = 0; it < 64; ++it) {
    const int cur  = it & 1;
    const int key0 = kbase0 + it * 128;

    __syncthreads();  // tile `it` landed (drains vmcnt); buf[cur^1] free

    // --- prefetch tile it+1 into the other buffer ---
    if (it < 63) {
      const int keyn = key0 + 128;
      const char* kg = kgbase + (size_t)keyn * 128;
      load_lds16(kg + ksrc_off, (char*)sm.main.kbuf[cur ^ 1] + kldsoff);
      const int sfrmn = keyn >> 12;
      const unsigned short* vg =
          vbf + (size_t)((sfrmn * NB + b) * CV) * HWN + (keyn & 4095);
      load_lds16(vg + vsrc_off, (char*)sm.main.vbuf[cur ^ 1] + vldsoff);
    }

    // --- K A-fragments from LDS (swizzled) ---
    f16x8 kf[2][2];
    #pragma unroll
    for (int g = 0; g < 2; ++g) {
      const int klr = kq * 32 + g * 16 + l15;
      const int swz = klr & 7;
      const _Float16* kb = &sm.main.kbuf[cur][klr * 64];
      #pragma unroll
      for (int h = 0; h < 2; ++h) {
        const int slot = (h * 4 + quad) ^ swz;
        kf[g][h] = *(const f16x8*)(kb + slot * 8);
      }
    }

    // --- V B-fragments: interleaved layout -> ONE b128 per cf at chunk
    //     (kq*4+quad)^swz, content = keys {g0: quad*4+r, g1: 16+quad*4+r} ---
    bf16x8 vf[4];
    {
      const int ch = kq * 4 + quad;
      #pragma unroll
      for (int cf = 0; cf < 4; ++cf) {
        const int cv  = cf * 16 + l15;
        const int swz = cv & 7;
        vf[cf] = ld_bf8_lds(&sm.main.vbuf[cur][cv * 128 + ((ch ^ swz) << 3)]);
      }
    }

    // --- S^T = K @ Q^T with folded bias: sf = S*log2e - SBIAS2 ---
    f32x4 sf[2][2];
    __builtin_amdgcn_s_setprio(1);
    #pragma unroll
    for (int g = 0; g < 2; ++g)
      #pragma unroll
      for (int f = 0; f < 2; ++f) {
        f32x4 acc = (f32x4){-SBIAS2, -SBIAS2, -SBIAS2, -SBIAS2};
        acc = __builtin_amdgcn_mfma_f32_16x16x32_f16(kf[g][0], qf[f][0], acc, 0, 0, 0);
        acc = __builtin_amdgcn_mfma_f32_16x16x32_f16(kf[g][1], qf[f][1], acc, 0, 0, 0);
        sf[g][f] = acc;
      }
    __builtin_amdgcn_s_setprio(0);

    // --- P = 2^sf, truncation-packed via v_perm; pf is lane-local (pi) ---
    #pragma unroll
    for (int f = 0; f < 2; ++f) {
      uint32_t pk[2][2];
      #pragma unroll
      for (int g = 0; g < 2; ++g) {
        float e0 = __builtin_amdgcn_exp2f(sf[g][f][0]);
        float e1 = __builtin_amdgcn_exp2f(sf[g][f][1]);
        float e2 = __builtin_amdgcn_exp2f(sf[g][f][2]);
        float e3 = __builtin_amdgcn_exp2f(sf[g][f][3]);
        pk[g][0] = __builtin_amdgcn_perm(__builtin_bit_cast(uint32_t, e1),
                                         __builtin_bit_cast(uint32_t, e0),
                                         0x07060302u);
        pk[g][1] = __builtin_amdgcn_perm(__builtin_bit_cast(uint32_t, e3),
                                         __builtin_bit_cast(uint32_t, e2),
                                         0x07060302u);
      }
      bf16x8 pf = __builtin_bit_cast(bf16x8,
          (u32x4){pk[0][0], pk[0][1], pk[1][0], pk[1][1]});

      __builtin_amdgcn_s_setprio(1);
      #pragma unroll
      for (int cf = 0; cf < 4; ++cf)
        Of[f][cf] = __builtin_amdgcn_mfma_f32_16x16x32_bf16(pf, vf[cf], Of[f][cf], 0, 0, 0);
      Ol[f] = __builtin_amdgcn_mfma_f32_16x16x32_bf16(pf, vones, Ol[f], 0, 0, 0);
      __builtin_amdgcn_s_setprio(0);
    }
  }

  __syncthreads();  // all waves done with main region before epi alias

  // --- Epilogue: 4 rg phases; reduce 4 kq waves per phase, store partials ---
  #pragma unroll
  for (int phase = 0; phase < 4; ++phase) {
    if (rg == phase) {
      #pragma unroll
      for (int f = 0; f < 2; ++f)
        #pragma unroll
        for (int r = 0; r < 4; ++r) {
          const int row = f * 16 + quad * 4 + r;     // 0..31
          if (l15 == 0) sm.epi.dbuf[kq][row] = Ol[f][r];
          #pragma unroll
          for (int cf = 0; cf < 4; ++cf)
            sm.epi.obuf[kq][row][cf * 16 + l15] = Of[f][cf][r];
        }
    }
    __syncthreads();
    if (t < 512) {
      const int row = t >> 4;                        // 0..31
      const int v4  = (t & 15) * 4;
      f32x4 acc = *(const f32x4*)&sm.epi.obuf[0][row][v4];
      #pragma unroll
      for (int q = 1; q < 4; ++q)
        acc += *(const f32x4*)&sm.epi.obuf[q][row][v4];
      *(f32x4*)&onum[((size_t)(ks * NB + b) * HWN + n0 + phase * 32 + row) * CV + v4] = acc;
      if (t < 32) {
        float d = sm.epi.dbuf[0][t] + sm.epi.dbuf[1][t] +
                  sm.epi.dbuf[2][t] + sm.epi.dbuf[3][t];
        odenom[(size_t)(ks * NB + b) * HWN + n0 + phase * 32 + t] = d;
      }
    }
    __syncthreads();
  }
}

// ---------------------------------------------------------------------------
// Finalize: out[b][v][hw] = sum_ks onum / sum_ks odenom + mask
// Grid NB*(HWN/16) = 512 blocks (16 hw rows each) -> 2 blocks/CU, all CUs
// busy (cross-XCD onum reads are remote-L2/HBM -- parallelism hides them).
// ---------------------------------------------------------------------------
__global__ __launch_bounds__(256) void finalize_k(
    const float* __restrict__ onum, const float* __restrict__ odenom,
    const float* __restrict__ maskpart, float* __restrict__ out)
{
  __shared__ float tile[16][68];
  __shared__ float dinv[16];
  __shared__ float ml[64];
  const int t   = threadIdx.x;
  const int b   = blockIdx.x >> 8;          // 256 blocks per batch
  const int hw0 = (blockIdx.x & 255) * 16;

  {
    const int row = t >> 4;                 // 0..15
    const int v4  = (t & 15) * 4;
    f32x4 acc = (f32x4){0.f, 0.f, 0.f, 0.f};
    #pragma unroll
    for (int ks = 0; ks < KS; ++ks)
      acc += *(const f32x4*)&onum[((size_t)(ks * NB + b) * HWN + hw0 + row) * CV + v4];
    *(f32x4*)&tile[row][v4] = acc;
  }
  if (t < 16) {
    float d = 0.f;
    #pragma unroll
    for (int ks = 0; ks < KS; ++ks)
      d += odenom[(size_t)(ks * NB + b) * HWN + hw0 + t];
    dinv[t] = 1.f / fmaxf(d, 1e-30f);
  }
  if (t >= 64 && t < 128) {
    float m = 0.f;
    #pragma unroll
    for (int s = 0; s < NS; ++s) m += maskpart[(b * CV + (t - 64)) * NS + s];
    ml[t - 64] = m;
  }
  __syncthreads();

  {
    const int v   = t >> 2;                 // 0..63
    const int hw4 = (t & 3) * 4;            // 0..12
    f32x4 o;
    #pragma unroll
    for (int j = 0; j < 4; ++j)
      o[j] = tile[hw4 + j][v] * dinv[hw4 + j] + ml[v];
    *(f32x4*)&out[((size_t)(b * CV + v)) * HWN + hw0 + hw4] = o;
  }
}

// ---------------------------------------------------------------------------
// Round-6 attention (fallback, small ws) -- reads interleaved vbf
// ---------------------------------------------------------------------------
struct __align__(16) SmemF {
  union {
    float qs[TM * QS_STR];
    unsigned short p[NW][2][16 * P_STR];
    struct {
      float obuf[NW][TM][CV];
      float lbuf[NW][TM];
    } epi;
  };
};

__global__ __launch_bounds__(512) void attn_fast(
    const _Float16* __restrict__ kT, const unsigned short* __restrict__ vbf,
    const float* __restrict__ query, const float* __restrict__ maskpart,
    float* __restrict__ out)
{
  __shared__ SmemF sm;
  const int t    = threadIdx.x;
  const int w    = t >> 6;
  const int lane = t & 63;
  const int quad = lane >> 4;
  const int l15  = lane & 15;
  const int bidx = blockIdx.x;
  const int b    = bidx & 1;
  const int n0   = ((bidx >> 1) & 127) * TM;

  if (t < 256) {
    const int qc   = t >> 2;
    const int noff = (t & 3) * 8;
    const int slot = qc ^ ((t & 3) << 2);
    const float* qp = query + (size_t)(b * CK + qc) * HWN + n0 + noff;
    f32x4 q0 = *(const f32x4*)(qp);
    f32x4 q1 = *(const f32x4*)(qp + 4);
    #pragma unroll
    for (int j = 0; j < 4; ++j) {
      sm.qs[(noff + j)     * QS_STR + slot] = q0[j];
      sm.qs[(noff + 4 + j) * QS_STR + slot] = q1[j];
    }
  }
  __syncthreads();
  f16x8 qf[2][2];
  #pragma unroll
  for (int f = 0; f < 2; ++f) {
    const int n  = f * 16 + l15;
    const int sw = ((n >> 3) & 7) << 2;
    const float* base = &sm.qs[n * QS_STR];
    #pragma unroll
    for (int h = 0; h < 2; ++h) {
      const int c0 = (h * 32 + quad * 8) ^ sw;
      f32x4 a  = *(const f32x4*)(base + c0);
      f32x4 bb = *(const f32x4*)(base + (c0 ^ 4));
      f16x8 q;
      #pragma unroll
      for (int j = 0; j < 4; ++j) { q[j] = (_Float16)a[j]; q[4 + j] = (_Float16)bb[j]; }
      qf[f][h] = q;
    }
  }
  __syncthreads();

  f32x4 Of[2][4];
  f32x4 Ol[2];
  #pragma unroll
  for (int f = 0; f < 2; ++f) {
    #pragma unroll
    for (int cf = 0; cf < 4; ++cf) Of[f][cf] = (f32x4){0.f, 0.f, 0.f, 0.f};
    Ol[f] = (f32x4){0.f, 0.f, 0.f, 0.f};
  }
  bf16x8 vones;
  #pragma unroll
  for (int i = 0; i < 8; ++i)
    vones[i] = __builtin_bit_cast(__bf16, (unsigned short)0x3F80);

  const _Float16* kbase = kT + (size_t)b * SHW * CK;

  for (int it = 0; it < SHW / 256; ++it) {
    const int key0 = it * 256 + w * 32;
    f16x8 kf[2][2];
    #pragma unroll
    for (int g = 0; g < 2; ++g)
      #pragma unroll
      for (int h = 0; h < 2; ++h)
        kf[g][h] = *(const f16x8*)(kbase +
            (size_t)(key0 + g * 16 + l15) * CK + h * 32 + quad * 8);

    const int s   = it >> 4;
    const int hwg = (it & 15) * 256 + w * 32;
    const int pa  = ((2 * quad) & 3) * 2 + (quad >> 1);
    const int pb  = ((2 * quad + 1) & 3) * 2 + (quad >> 1);
    bf16x8 vf[4];
    #pragma unroll
    for (int cf = 0; cf < 4; ++cf) {
      const unsigned short* rowp = vbf +
          ((size_t)((s * NB + b) * CV + cf * 16 + l15)) * HWN + hwg;
      u32x2 lo = *(const u32x2*)(rowp + pa * 4);
      u32x2 hi = *(const u32x2*)(rowp + pb * 4);
      vf[cf] = __builtin_bit_cast(bf16x8, (u32x4){lo.x, lo.y, hi.x, hi.y});
    }

    f32x4 sfv[2][2];
    #pragma unroll
    for (int f = 0; f < 2; ++f)
      #pragma unroll
      for (int g = 0; g < 2; ++g) {
        f32x4 acc = (f32x4){0.f, 0.f, 0.f, 0.f};
        acc = __builtin_amdgcn_mfma_f32_16x16x32_f16(qf[f][0], kf[g][0], acc, 0, 0, 0);
        acc = __builtin_amdgcn_mfma_f32_16x16x32_f16(qf[f][1], kf[g][1], acc, 0, 0, 0);
        sfv[f][g] = acc;
      }

    #pragma unroll
    for (int f = 0; f < 2; ++f)
      #pragma unroll
      for (int g = 0; g < 2; ++g)
        #pragma unroll
        for (int r = 0; r < 4; ++r)
          sfv[f][g][r] = __expf(sfv[f][g][r] - SBIAS);

    #pragma unroll
    for (int f = 0; f < 2; ++f)
      #pragma unroll
      for (int g = 0; g < 2; ++g)
        #pragma unroll
        for (int r = 0; r < 4; ++r)
          sm.p[w][f][(quad * 4 + r) * P_STR + g * 16 + l15] = f2bfu(sfv[f][g][r]);
    asm volatile("s_waitcnt lgkmcnt(0)" ::: "memory");
    bf16x8 pf[2];
    #pragma unroll
    for (int f = 0; f < 2; ++f)
      pf[f] = ld_bf8_lds(&sm.p[w][f][l15 * P_STR + quad * 8]);

    #pragma unroll
    for (int f = 0; f < 2; ++f) {
      #pragma unroll
      for (int cf = 0; cf < 4; ++cf)
        Of[f][cf] = __builtin_amdgcn_mfma_f32_16x16x32_bf16(pf[f], vf[cf], Of[f][cf], 0, 0, 0);
      Ol[f] = __builtin_amdgcn_mfma_f32_16x16x32_bf16(pf[f], vones, Ol[f], 0, 0, 0);
    }
  }

  __syncthreads();
  #pragma unroll
  for (int f = 0; f < 2; ++f)
    #pragma unroll
    for (int r = 0; r < 4; ++r) {
      const int row = f * 16 + quad * 4 + r;
      if (l15 == 0) sm.epi.lbuf[w][row] = Ol[f][r];
      #pragma unroll
      for (int cf = 0; cf < 4; ++cf)
        sm.epi.obuf[w][row][cf * 16 + l15] = Of[f][cf][r];
    }
  __syncthreads();
  {
    const int n   = t & 31;
    const int vhi = t >> 5;
    float denom = 0.f;
    #pragma unroll
    for (int ww = 0; ww < NW; ++ww) denom += sm.epi.lbuf[ww][n];
    const float inv = 1.f / fmaxf(denom, 1e-30f);
    #pragma unroll
    for (int g = 0; g < 4; ++g) {
      const int v = vhi + 16 * g;
      float num = 0.f;
      #pragma unroll
      for (int ww = 0; ww < NW; ++ww) num += sm.epi.obuf[ww][n][v];
      float mlv = 0.f;
      #pragma unroll
      for (int s = 0; s < NS; ++s) mlv += maskpart[(b * CV + v) * NS + s];
      out[((size_t)(b * CV + v)) * HWN + n0 + n] = num * inv + mlv;
    }
  }
}

// ---------------------------------------------------------------------------
extern "C" void kernel_launch(void* const* d_in, const int* in_sizes, int n_in,
                              void* d_out, int out_size, void* d_ws, size_t ws_size,
                              hipStream_t stream) {
  const float* keys  = (const float*)d_in[0];
  const float* vals  = (const float*)d_in[1];
  const float* query = (const float*)d_in[2];
  const float* disp  = (const float*)d_in[3];
  const int*   seq   = (const int*)d_in[4];
  float*       out   = (float*)d_out;

  _Float16*       kT    = (_Float16*)d_ws;
  unsigned short* vbf   = (unsigned short*)((char*)d_ws + KT_BYTES);
  float*          maskp = (float*)((char*)d_ws + MASKP_OFF);

  prep_all<<<512 + NB * NS * CV, 512, 0, stream>>>(keys, vals, disp, seq,
                                                   kT, vbf, maskp);

  if (ws_size >= WS2) {
    float* onum   = (float*)((char*)d_ws + ONUM_OFF);
    float* odenom = (float*)((char*)d_ws + ODEN_OFF);
    attn_v6<<<NB * 32 * KS, 1024, 0, stream>>>(kT, vbf, query, onum, odenom);
    finalize_k<<<NB * (HWN / 16), 256, 0, stream>>>(onum, odenom, maskp, out);
  } else {
    attn_fast<<<NB * (HWN / TM), 512, 0, stream>>>(kT, vbf, query, maskp, out);
  }
}